// Round 20
// baseline (198.287 us; speedup 1.0000x reference)
//
#include <hip/hip_runtime.h>
#include <hip/hip_bf16.h>
#include <stdint.h>

typedef unsigned short u16;
typedef __bf16 bf16x8 __attribute__((ext_vector_type(8)));
typedef float f32x4 __attribute__((ext_vector_type(4)));

#define MFMA16(a, b, c) __builtin_amdgcn_mfma_f32_16x16x32_bf16((a), (b), (c), 0, 0, 0)

#define GLOAD16(g, l)                                                        \
  __builtin_amdgcn_global_load_lds(                                          \
      (const __attribute__((address_space(1))) void*)(g),                    \
      (__attribute__((address_space(3))) void*)(l), 16, 0, 0)

static __device__ __forceinline__ u16 f2bf(float f) {
  union { float f; uint32_t u; } v;
  v.f = f;
  uint32_t u = v.u;
  return (u16)((u + 0x7FFFu + ((u >> 16) & 1u)) >> 16);  // RNE
}
static __device__ __forceinline__ float u2f(uint32_t u) {
  union { uint32_t u; float f; } v;
  v.u = u;
  return v.f;
}

// ---- workspace layout (u16 elements) ----
#define FEATT_ELEMS (8u * 98u * 98u * 256u)   // [b][h+1][w+1][c] bf16, zero halo
#define W1T_OFF     FEATT_ELEMS               // [oc][tap][cin] bf16: 256*2304
#define W1T_ELEMS   (256u * 2304u)
#define W2B_OFF     (W1T_OFF + W1T_ELEMS)     // [576][256] bf16
#define W2B_ELEMS   (576u * 256u)
#define X_OFF       (W2B_OFF + W2B_ELEMS)     // [73728][256] bf16

// ---------------- merged prep: halo zero | featT transpose | weights ------------
__global__ __launch_bounds__(256) void prep_all(const float* __restrict__ feat,
                                                const float* __restrict__ w1,
                                                const float* __restrict__ w2,
                                                u16* __restrict__ featT,
                                                u16* __restrict__ w1t,
                                                u16* __restrict__ w2b) {
  const int blk = blockIdx.x;
  const int t = threadIdx.x;
  if (blk < 388) {
    int tid = blk * 256 + t;
    int b = tid / (388 * 32);
    int rem = tid % (388 * 32);
    int pos = rem >> 5, v = rem & 31;
    int h, w;
    if (pos < 98) { h = 0; w = pos; }
    else if (pos < 196) { h = 97; w = pos - 98; }
    else if (pos < 292) { h = pos - 196 + 1; w = 0; }
    else { h = pos - 292 + 1; w = 97; }
    uint4* dst = (uint4*)(featT + (size_t)((b * 98 + h) * 98 + w) * 256 + v * 8);
    *dst = make_uint4(0, 0, 0, 0);
  } else if (blk < 4996) {
    int idx = blk - 388;
    int pt = idx % 144, ct = (idx / 144) & 3, b = idx / 576;
    const int p0 = pt * 64, c0 = ct * 64;
    __shared__ float tile[64][65];
    const int pj = t & 63, ci0 = t >> 6;
#pragma unroll
    for (int r = 0; r < 16; ++r) {
      int ci = r * 4 + ci0;
      tile[ci][pj] = feat[(b * 256 + c0 + ci) * 9216 + p0 + pj];
    }
    __syncthreads();
    const int pl = t >> 2, cc0 = (t & 3) * 16;
    const int pix = p0 + pl;
    const int h = pix / 96, w = pix % 96;
    uint32_t u[8];
#pragma unroll
    for (int i = 0; i < 8; ++i) {
      u16 lo = f2bf(tile[cc0 + 2 * i][pl]);
      u16 hi = f2bf(tile[cc0 + 2 * i + 1][pl]);
      u[i] = (uint32_t)lo | ((uint32_t)hi << 16);
    }
    uint4* dst = (uint4*)(featT + (size_t)((b * 98 + h + 1) * 98 + (w + 1)) * 256 + c0 + cc0);
    dst[0] = make_uint4(u[0], u[1], u[2], u[3]);
    dst[1] = make_uint4(u[4], u[5], u[6], u[7]);
  } else {
    int i = (blk - 4996) * 256 + t;
    if (i < 589824) {
      int oc = i / 2304, r = i % 2304;
      int tap = r >> 8, cin = r & 255;
      w1t[i] = f2bf(w1[(oc * 256 + cin) * 9 + tap]);
    } else {
      int j = i - 589824;
      if (j < 147456) w2b[j] = f2bf(w2[j]);
    }
  }
}

// ------- GEMM1P: BK=32 double-buffer, stage-before-compute, ONE barrier/step ----
// LDS 2 x 24KB (sA 128x32, sB 256x32) + sb1 = ~49KB -> 2 blocks/CU.
// Per step per wave: 3 gloads (issued first), 8 ds_read_b128, 16 MFMA, 1 barrier.
// Stage latency hides under compute; barrier drain finds loads already landed.
// Fragment swizzle: 32-elem rows, 4-chunk XOR sigma(row)=row&3 (conflict-free).
__global__ __launch_bounds__(512, 4) void gemm1p(const u16* __restrict__ featT,
                                                 const u16* __restrict__ w1t,
                                                 const float* __restrict__ b1,
                                                 u16* __restrict__ xout) {
  __shared__ __align__(16) u16 smem[2 * 12288];  // buf: [0,4096)=A, [4096,12288)=B
  __shared__ float sb1[256];

  const int t = threadIdx.x;
  const int wave = t >> 6, lane = t & 63;
  const int bid = blockIdx.x;
  const int mt = (bid & 7) * 72 + (bid >> 3);  // bijective XCD swizzle (576%8==0)
  const int b = mt / 72;
  const int ip0 = (mt % 72) * 128;

  if (t < 256) sb1[t] = b1[t];

  // staging bases (pre-swizzled source chunk, sigma(row)=row&3 in 4-chunk space)
  const u16* aSrc;
  {
    int rowA = wave * 16 + (lane >> 2);          // 0..127
    int jA = (lane & 3) ^ (rowA & 3);
    int ip = ip0 + rowA;
    int h = ip / 96, w = ip % 96;
    aSrc = featT + (size_t)((b * 98 + h + 1) * 98 + (w + 1)) * 256 + jA * 8;
  }
  const u16* bSrc[2];
#pragma unroll
  for (int r = 0; r < 2; ++r) {
    int rowB = wave * 32 + r * 16 + (lane >> 2);  // 0..255
    int jB = (lane & 3) ^ (rowB & 3);
    bSrc[r] = w1t + (size_t)rowB * 2304 + jB * 8;
  }

  auto stage = [&](int kt, int bufi) {
    int tap = kt >> 3;
    int dh = tap / 3 - 1, dw = tap % 3 - 1;
    int aoff = (dh * 98 + dw) * 256 + (kt & 7) * 32;
    int boff = kt * 32;
    u16* base = &smem[bufi * 12288];
    GLOAD16(aSrc + aoff, base + wave * 512);
    GLOAD16(bSrc[0] + boff, base + 4096 + wave * 1024);
    GLOAD16(bSrc[1] + boff, base + 4096 + wave * 1024 + 512);
  };

  const int wm = wave >> 2, wn = wave & 3;
  const int l15 = lane & 15, kcc = lane >> 4;  // kcc 0..3 (one 8-chunk of 32)
  int aoffs[4], boffs[4];
#pragma unroll
  for (int m = 0; m < 4; ++m) {
    int rowa = wm * 64 + m * 16 + l15;
    aoffs[m] = rowa * 32 + ((kcc ^ (rowa & 3)) * 8);
  }
#pragma unroll
  for (int n = 0; n < 4; ++n) {
    int rowb = wn * 64 + n * 16 + l15;
    boffs[n] = 4096 + rowb * 32 + ((kcc ^ (rowb & 3)) * 8);
  }

  f32x4 acc[4][4];
#pragma unroll
  for (int m = 0; m < 4; ++m)
#pragma unroll
    for (int n = 0; n < 4; ++n) acc[m][n] = f32x4{0.f, 0.f, 0.f, 0.f};

  stage(0, 0);
  __syncthreads();  // tile 0 landed (full drain)
  int buf = 0;
  for (int kt = 0; kt < 72; ++kt) {
    if (kt < 71) stage(kt + 1, buf ^ 1);  // issue next tile FIRST (hides latency)
    const u16* base = &smem[buf * 12288];
    bf16x8 av[4], bv[4];
#pragma unroll
    for (int m = 0; m < 4; ++m) av[m] = *(const bf16x8*)&base[aoffs[m]];
#pragma unroll
    for (int n = 0; n < 4; ++n) bv[n] = *(const bf16x8*)&base[boffs[n]];
#pragma unroll
    for (int m = 0; m < 4; ++m)
#pragma unroll
      for (int n = 0; n < 4; ++n) acc[m][n] = MFMA16(av[m], bv[n], acc[m][n]);
    __syncthreads();  // drains: stage(kt+1) landed AND all reads of buf done
    buf ^= 1;
  }

  const int pix0g = mt * 128;
#pragma unroll
  for (int m = 0; m < 4; ++m) {
    int pixl = wm * 64 + m * 16 + ((lane >> 4) << 2);
#pragma unroll
    for (int n = 0; n < 4; ++n) {
      int oc = wn * 64 + n * 16 + l15;
      float bias = sb1[oc];
      f32x4 v = acc[m][n];
#pragma unroll
      for (int j = 0; j < 4; ++j) {
        float val = v[j] + bias;
        val = val > 0.f ? val : 0.f;
        xout[(size_t)(pix0g + pixl + j) * 256 + oc] = f2bf(val);
      }
    }
  }
}

// ------- GEMM2FQ (r16-proven) + slim epilogue (no max-subtraction) --------------
__global__ __launch_bounds__(512) void gemm2fq(const u16* __restrict__ xws,
                                               const u16* __restrict__ w2b,
                                               const float* __restrict__ b2g,
                                               const float* __restrict__ flow,
                                               float* __restrict__ out) {
  __shared__ __align__(16) u16 sW[2][9216];  // 2 x [144][64] bf16 = 36864 B
  __shared__ uint32_t sFlowP[1152];          // [9][128] packed (fy<<16)|fx, 4608 B
  __shared__ float sb2f[576];                // 2304 B  -> total 43776 B

  const int t = threadIdx.x;
  const int wave = t >> 6, lane = t & 63;
  const int bid = blockIdx.x;
  const int mt = (bid & 7) * 72 + (bid >> 3);  // bijective XCD swizzle (576%8==0)
  const int b = mt / 72;
  const int ipl0 = (mt % 72) * 128;
  const int l15 = lane & 15, kc = lane >> 4;

  auto stageQ = [&](int u, int bufi) {
    int cI = u >> 2, kq = u & 3;
    if (t < 384) {  // wave-uniform (waves 0-5)
#pragma unroll
      for (int pass = 0; pass < 3; ++pass) {
        int c = pass * 384 + t;  // 0..1151
        int n = c >> 3, cl = c & 7;
        int cg = cl ^ (n & 7);
        int chan = (n >> 4) * 64 + cI * 16 + (n & 15);
        GLOAD16(w2b + (size_t)chan * 256 + kq * 64 + cg * 8,
                &sW[bufi][(pass * 384 + wave * 64) * 8]);
      }
    }
  };
  stageQ(0, 0);  // overlaps setup below

  for (int i = t; i < 1152; i += 512) {
    int nf = i >> 7, p = i & 127;
    int ip = ipl0 + p;
    int h = ip / 96, w = ip % 96;
    int hh = h + nf / 3 - 1, ww = w + nf % 3 - 1;
    float vx = 0.f, vy = 0.f;
    if (hh >= 0 && hh < 96 && ww >= 0 && ww < 96) {
      vx = flow[b * 18432 + hh * 96 + ww];
      vy = flow[b * 18432 + 9216 + hh * 96 + ww];
    }
    sFlowP[i] = (uint32_t)f2bf(vx) | ((uint32_t)f2bf(vy) << 16);
  }
  for (int i = t; i < 576; i += 512) sb2f[i] = b2g[i];

  const int px = wave * 16 + l15;  // 0..127
  const u16* xr = &xws[((size_t)mt * 128 + px) * 256];
  bf16x8 areg[8];
#pragma unroll
  for (int s = 0; s < 8; ++s) areg[s] = *(const bf16x8*)&xr[(s * 4 + kc) * 8];

  const int iph = (ipl0 + px) / 96, ipw = (ipl0 + px) % 96;
  const size_t ob = ((size_t)(b * 2) * 768 + iph * 8) * 768 + ipw * 8;
  const int q0 = (kc & 1) * 4, pk = kc >> 1;

  uint32_t fp[9];
  f32x4 acc[9];
#pragma unroll
  for (int u = 0; u < 16; ++u) {
    __syncthreads();  // stage(u) landed (implicit vmcnt drain); old buf reads done
    if (u == 0) {
#pragma unroll
      for (int nf = 0; nf < 9; ++nf) fp[nf] = sFlowP[nf * 128 + px];
    }
    if (u < 15) stageQ(u + 1, (u + 1) & 1);  // fills other buf under compute
    const int cI = u >> 2, kq = u & 3;
    if (kq == 0) {
#pragma unroll
      for (int nf = 0; nf < 9; ++nf) acc[nf] = f32x4{0.f, 0.f, 0.f, 0.f};
    }
    const u16* base = sW[u & 1];
    __builtin_amdgcn_s_setprio(1);
#pragma unroll
    for (int ki = 0; ki < 2; ++ki) {
      bf16x8 a = areg[kq * 2 + ki];  // static (loop fully unrolled)
      int kcc = ki * 4 + kc;         // 0..7 within the quarter
#pragma unroll
      for (int nf = 0; nf < 9; ++nf) {
        int n = nf * 16 + l15;
        bf16x8 wv = *(const bf16x8*)&base[n * 64 + ((kcc ^ (n & 7)) * 8)];
        acc[nf] = MFMA16(wv, a, acc[nf]);
      }
    }
    __builtin_amdgcn_s_setprio(0);
    if (kq == 3) {
      // slim softmax (logits bounded ~|3| -> no max-subtraction needed) + combine
      f32x4 vx4, vy4;
#pragma unroll
      for (int j = 0; j < 4; ++j) {
        int pql = kc * 4 + j;
        float ssum = 0.f, fx = 0.f, fy = 0.f;
#pragma unroll
        for (int nf = 0; nf < 9; ++nf) {
          float e = __expf(acc[nf][j] + sb2f[nf * 64 + cI * 16 + pql]);
          ssum += e;
          fx += e * u2f(fp[nf] << 16);
          fy += e * u2f(fp[nf] & 0xFFFF0000u);
        }
        float sc = 8.0f / ssum;
        vx4[j] = fx * sc;
        vy4[j] = fy * sc;
      }
      int p = cI * 2 + pk;
      *(f32x4*)&out[ob + (size_t)p * 768 + q0] = vx4;
      *(f32x4*)&out[ob + 589824 + (size_t)p * 768 + q0] = vy4;
    }
  }
}

extern "C" void kernel_launch(void* const* d_in, const int* in_sizes, int n_in,
                              void* d_out, int out_size, void* d_ws, size_t ws_size,
                              hipStream_t stream) {
  const float* flow = (const float*)d_in[0];
  const float* feat = (const float*)d_in[1];
  const float* w1 = (const float*)d_in[2];
  const float* b1 = (const float*)d_in[3];
  const float* w2 = (const float*)d_in[4];
  const float* b2 = (const float*)d_in[5];
  float* out = (float*)d_out;
  u16* ws = (u16*)d_ws;
  u16* featT = ws;
  u16* w1t = ws + W1T_OFF;
  u16* w2b = ws + W2B_OFF;
  u16* xws = ws + X_OFF;

  prep_all<<<7876, 256, 0, stream>>>(feat, w1, w2, featT, w1t, w2b);
  gemm1p<<<576, 512, 0, stream>>>(featT, w1t, b1, xws);
  gemm2fq<<<576, 512, 0, stream>>>(xws, w2b, b2, flow, out);
}

// Round 21
// 183.939 us; speedup vs baseline: 1.0780x; 1.0780x over previous
//
#include <hip/hip_runtime.h>
#include <hip/hip_bf16.h>
#include <stdint.h>

typedef unsigned short u16;
typedef __bf16 bf16x8 __attribute__((ext_vector_type(8)));
typedef float f32x4 __attribute__((ext_vector_type(4)));

#define MFMA16(a, b, c) __builtin_amdgcn_mfma_f32_16x16x32_bf16((a), (b), (c), 0, 0, 0)

#define GLOAD16(g, l)                                                        \
  __builtin_amdgcn_global_load_lds(                                          \
      (const __attribute__((address_space(1))) void*)(g),                    \
      (__attribute__((address_space(3))) void*)(l), 16, 0, 0)

static __device__ __forceinline__ u16 f2bf(float f) {
  union { float f; uint32_t u; } v;
  v.f = f;
  uint32_t u = v.u;
  return (u16)((u + 0x7FFFu + ((u >> 16) & 1u)) >> 16);  // RNE
}
static __device__ __forceinline__ float u2f(uint32_t u) {
  union { uint32_t u; float f; } v;
  v.u = u;
  return v.f;
}

// ---- workspace layout (u16 elements) ----
#define FEATT_ELEMS (8u * 98u * 98u * 256u)   // [b][h+1][w+1][c] bf16, zero halo
#define W1T_OFF     FEATT_ELEMS               // [oc][tap][cin] bf16: 256*2304
#define W1T_ELEMS   (256u * 2304u)
#define W2B_OFF     (W1T_OFF + W1T_ELEMS)     // [576][256] bf16
#define W2B_ELEMS   (576u * 256u)
#define X_OFF       (W2B_OFF + W2B_ELEMS)     // [73728][256] bf16

// ---------------- merged prep: halo zero | featT transpose | weights ------------
__global__ __launch_bounds__(256) void prep_all(const float* __restrict__ feat,
                                                const float* __restrict__ w1,
                                                const float* __restrict__ w2,
                                                u16* __restrict__ featT,
                                                u16* __restrict__ w1t,
                                                u16* __restrict__ w2b) {
  const int blk = blockIdx.x;
  const int t = threadIdx.x;
  if (blk < 388) {
    int tid = blk * 256 + t;
    int b = tid / (388 * 32);
    int rem = tid % (388 * 32);
    int pos = rem >> 5, v = rem & 31;
    int h, w;
    if (pos < 98) { h = 0; w = pos; }
    else if (pos < 196) { h = 97; w = pos - 98; }
    else if (pos < 292) { h = pos - 196 + 1; w = 0; }
    else { h = pos - 292 + 1; w = 97; }
    uint4* dst = (uint4*)(featT + (size_t)((b * 98 + h) * 98 + w) * 256 + v * 8);
    *dst = make_uint4(0, 0, 0, 0);
  } else if (blk < 4996) {
    int idx = blk - 388;
    int pt = idx % 144, ct = (idx / 144) & 3, b = idx / 576;
    const int p0 = pt * 64, c0 = ct * 64;
    __shared__ float tile[64][65];
    const int pj = t & 63, ci0 = t >> 6;
#pragma unroll
    for (int r = 0; r < 16; ++r) {
      int ci = r * 4 + ci0;
      tile[ci][pj] = feat[(b * 256 + c0 + ci) * 9216 + p0 + pj];
    }
    __syncthreads();
    const int pl = t >> 2, cc0 = (t & 3) * 16;
    const int pix = p0 + pl;
    const int h = pix / 96, w = pix % 96;
    uint32_t u[8];
#pragma unroll
    for (int i = 0; i < 8; ++i) {
      u16 lo = f2bf(tile[cc0 + 2 * i][pl]);
      u16 hi = f2bf(tile[cc0 + 2 * i + 1][pl]);
      u[i] = (uint32_t)lo | ((uint32_t)hi << 16);
    }
    uint4* dst = (uint4*)(featT + (size_t)((b * 98 + h + 1) * 98 + (w + 1)) * 256 + c0 + cc0);
    dst[0] = make_uint4(u[0], u[1], u[2], u[3]);
    dst[1] = make_uint4(u[4], u[5], u[6], u[7]);
  } else {
    int i = (blk - 4996) * 256 + t;
    if (i < 589824) {
      int oc = i / 2304, r = i % 2304;
      int tap = r >> 8, cin = r & 255;
      w1t[i] = f2bf(w1[(oc * 256 + cin) * 9 + tap]);
    } else {
      int j = i - 589824;
      if (j < 147456) w2b[j] = f2bf(w2[j]);
    }
  }
}

// ---------------- GEMM1 (r19-proven: r2 structure + XCD swizzle) ----------------
__global__ __launch_bounds__(512, 4) void gemm1(const u16* __restrict__ featT,
                                                const u16* __restrict__ w1t,
                                                const float* __restrict__ b1,
                                                u16* __restrict__ xout) {
  __shared__ __align__(16) u16 sA[128 * 64];  // 16KB
  __shared__ __align__(16) u16 sB[256 * 64];  // 32KB
  __shared__ float sb1[256];

  const int t = threadIdx.x;
  const int wave = t >> 6, lane = t & 63;
  const int bid = blockIdx.x;
  const int mt = (bid & 7) * 72 + (bid >> 3);  // bijective XCD swizzle (576%8==0)
  const int b = mt / 72;
  const int ip0 = (mt % 72) * 128;

  if (t < 256) sb1[t] = b1[t];

  const u16* aBase[2];
  const u16* bBase[4];
#pragma unroll
  for (int r = 0; r < 2; ++r) {
    int row = r * 64 + wave * 8 + (lane >> 3);  // 0..127
    int chunk = (lane & 7) ^ (row & 7);
    int ip = ip0 + row;
    int h = ip / 96, w = ip % 96;
    aBase[r] = featT + (size_t)((b * 98 + h + 1) * 98 + (w + 1)) * 256 + chunk * 8;
  }
#pragma unroll
  for (int r = 0; r < 4; ++r) {
    int row = wave * 32 + r * 8 + (lane >> 3);  // 0..255
    int chunk = (lane & 7) ^ (row & 7);
    bBase[r] = w1t + (size_t)row * 2304 + chunk * 8;
  }

  const int wm = wave >> 2, wn = wave & 3;
  int aoffs[4][2], boffs[4][2];
#pragma unroll
  for (int m = 0; m < 4; ++m) {
#pragma unroll
    for (int ki = 0; ki < 2; ++ki) {
      int kc = ki * 4 + (lane >> 4);
      int rowa = wm * 64 + m * 16 + (lane & 15);
      aoffs[m][ki] = rowa * 64 + ((kc ^ (rowa & 7)) * 8);
      int rowb = wn * 64 + m * 16 + (lane & 15);
      boffs[m][ki] = rowb * 64 + ((kc ^ (rowb & 7)) * 8);
    }
  }

  f32x4 acc[4][4];
#pragma unroll
  for (int m = 0; m < 4; ++m)
#pragma unroll
    for (int n = 0; n < 4; ++n) acc[m][n] = f32x4{0.f, 0.f, 0.f, 0.f};

  for (int kt = 0; kt < 36; ++kt) {
    int tap = kt >> 2;
    int dh = tap / 3 - 1, dw = tap % 3 - 1;
    int aoff = (dh * 98 + dw) * 256 + (kt & 3) * 64;
    int boff = kt * 64;
#pragma unroll
    for (int r = 0; r < 2; ++r) GLOAD16(aBase[r] + aoff, &sA[(r * 64 + wave * 8) * 64]);
#pragma unroll
    for (int r = 0; r < 4; ++r) GLOAD16(bBase[r] + boff, &sB[(wave * 32 + r * 8) * 64]);
    __syncthreads();
#pragma unroll
    for (int ki = 0; ki < 2; ++ki) {
      bf16x8 av[4], bv[4];
#pragma unroll
      for (int m = 0; m < 4; ++m) av[m] = *(const bf16x8*)&sA[aoffs[m][ki]];
#pragma unroll
      for (int n = 0; n < 4; ++n) bv[n] = *(const bf16x8*)&sB[boffs[n][ki]];
#pragma unroll
      for (int m = 0; m < 4; ++m)
#pragma unroll
        for (int n = 0; n < 4; ++n) acc[m][n] = MFMA16(av[m], bv[n], acc[m][n]);
    }
    __syncthreads();
  }

  const int pix0g = mt * 128;
#pragma unroll
  for (int m = 0; m < 4; ++m) {
    int pixl = wm * 64 + m * 16 + ((lane >> 4) << 2);
#pragma unroll
    for (int n = 0; n < 4; ++n) {
      int oc = wn * 64 + n * 16 + (lane & 15);
      float bias = sb1[oc];
      f32x4 v = acc[m][n];
#pragma unroll
      for (int j = 0; j < 4; ++j) {
        float val = v[j] + bias;
        val = val > 0.f ? val : 0.f;
        xout[(size_t)(pix0g + pixl + j) * 256 + oc] = f2bf(val);
      }
    }
  }
}

// ------- GEMM2FQ (r16 structure + r20 slim epilogue) ----------------------------
__global__ __launch_bounds__(512) void gemm2fq(const u16* __restrict__ xws,
                                               const u16* __restrict__ w2b,
                                               const float* __restrict__ b2g,
                                               const float* __restrict__ flow,
                                               float* __restrict__ out) {
  __shared__ __align__(16) u16 sW[2][9216];  // 2 x [144][64] bf16 = 36864 B
  __shared__ uint32_t sFlowP[1152];          // [9][128] packed (fy<<16)|fx, 4608 B
  __shared__ float sb2f[576];                // 2304 B  -> total 43776 B

  const int t = threadIdx.x;
  const int wave = t >> 6, lane = t & 63;
  const int bid = blockIdx.x;
  const int mt = (bid & 7) * 72 + (bid >> 3);  // bijective XCD swizzle (576%8==0)
  const int b = mt / 72;
  const int ipl0 = (mt % 72) * 128;
  const int l15 = lane & 15, kc = lane >> 4;

  auto stageQ = [&](int u, int bufi) {
    int cI = u >> 2, kq = u & 3;
    if (t < 384) {  // wave-uniform (waves 0-5)
#pragma unroll
      for (int pass = 0; pass < 3; ++pass) {
        int c = pass * 384 + t;  // 0..1151
        int n = c >> 3, cl = c & 7;
        int cg = cl ^ (n & 7);
        int chan = (n >> 4) * 64 + cI * 16 + (n & 15);
        GLOAD16(w2b + (size_t)chan * 256 + kq * 64 + cg * 8,
                &sW[bufi][(pass * 384 + wave * 64) * 8]);
      }
    }
  };
  stageQ(0, 0);  // overlaps setup below

  for (int i = t; i < 1152; i += 512) {
    int nf = i >> 7, p = i & 127;
    int ip = ipl0 + p;
    int h = ip / 96, w = ip % 96;
    int hh = h + nf / 3 - 1, ww = w + nf % 3 - 1;
    float vx = 0.f, vy = 0.f;
    if (hh >= 0 && hh < 96 && ww >= 0 && ww < 96) {
      vx = flow[b * 18432 + hh * 96 + ww];
      vy = flow[b * 18432 + 9216 + hh * 96 + ww];
    }
    sFlowP[i] = (uint32_t)f2bf(vx) | ((uint32_t)f2bf(vy) << 16);
  }
  for (int i = t; i < 576; i += 512) sb2f[i] = b2g[i];

  const int px = wave * 16 + l15;  // 0..127
  const u16* xr = &xws[((size_t)mt * 128 + px) * 256];
  bf16x8 areg[8];
#pragma unroll
  for (int s = 0; s < 8; ++s) areg[s] = *(const bf16x8*)&xr[(s * 4 + kc) * 8];

  const int iph = (ipl0 + px) / 96, ipw = (ipl0 + px) % 96;
  const size_t ob = ((size_t)(b * 2) * 768 + iph * 8) * 768 + ipw * 8;
  const int q0 = (kc & 1) * 4, pk = kc >> 1;

  uint32_t fp[9];
  f32x4 acc[9];
#pragma unroll
  for (int u = 0; u < 16; ++u) {
    __syncthreads();  // stage(u) landed (implicit vmcnt drain); old buf reads done
    if (u == 0) {
#pragma unroll
      for (int nf = 0; nf < 9; ++nf) fp[nf] = sFlowP[nf * 128 + px];
    }
    if (u < 15) stageQ(u + 1, (u + 1) & 1);  // fills other buf under compute
    const int cI = u >> 2, kq = u & 3;
    if (kq == 0) {
#pragma unroll
      for (int nf = 0; nf < 9; ++nf) acc[nf] = f32x4{0.f, 0.f, 0.f, 0.f};
    }
    const u16* base = sW[u & 1];
    __builtin_amdgcn_s_setprio(1);
#pragma unroll
    for (int ki = 0; ki < 2; ++ki) {
      bf16x8 a = areg[kq * 2 + ki];  // static (loop fully unrolled)
      int kcc = ki * 4 + kc;         // 0..7 within the quarter
#pragma unroll
      for (int nf = 0; nf < 9; ++nf) {
        int n = nf * 16 + l15;
        bf16x8 wv = *(const bf16x8*)&base[n * 64 + ((kcc ^ (n & 7)) * 8)];
        acc[nf] = MFMA16(wv, a, acc[nf]);
      }
    }
    __builtin_amdgcn_s_setprio(0);
    if (kq == 3) {
      // slim softmax (logits bounded ~|3| -> no max-subtraction needed) + combine
      f32x4 vx4, vy4;
#pragma unroll
      for (int j = 0; j < 4; ++j) {
        int pql = kc * 4 + j;
        float ssum = 0.f, fx = 0.f, fy = 0.f;
#pragma unroll
        for (int nf = 0; nf < 9; ++nf) {
          float e = __expf(acc[nf][j] + sb2f[nf * 64 + cI * 16 + pql]);
          ssum += e;
          fx += e * u2f(fp[nf] << 16);
          fy += e * u2f(fp[nf] & 0xFFFF0000u);
        }
        float sc = 8.0f / ssum;
        vx4[j] = fx * sc;
        vy4[j] = fy * sc;
      }
      int p = cI * 2 + pk;
      *(f32x4*)&out[ob + (size_t)p * 768 + q0] = vx4;
      *(f32x4*)&out[ob + 589824 + (size_t)p * 768 + q0] = vy4;
    }
  }
}

extern "C" void kernel_launch(void* const* d_in, const int* in_sizes, int n_in,
                              void* d_out, int out_size, void* d_ws, size_t ws_size,
                              hipStream_t stream) {
  const float* flow = (const float*)d_in[0];
  const float* feat = (const float*)d_in[1];
  const float* w1 = (const float*)d_in[2];
  const float* b1 = (const float*)d_in[3];
  const float* w2 = (const float*)d_in[4];
  const float* b2 = (const float*)d_in[5];
  float* out = (float*)d_out;
  u16* ws = (u16*)d_ws;
  u16* featT = ws;
  u16* w1t = ws + W1T_OFF;
  u16* w2b = ws + W2B_OFF;
  u16* xws = ws + X_OFF;

  prep_all<<<7876, 256, 0, stream>>>(feat, w1, w2, featT, w1t, w2b);
  gemm1<<<576, 512, 0, stream>>>(featT, w1t, b1, xws);
  gemm2fq<<<576, 512, 0, stream>>>(xws, w2b, b2, flow, out);
}

// Round 22
// 182.231 us; speedup vs baseline: 1.0881x; 1.0094x over previous
//
#include <hip/hip_runtime.h>
#include <hip/hip_bf16.h>
#include <stdint.h>

typedef unsigned short u16;
typedef __bf16 bf16x8 __attribute__((ext_vector_type(8)));
typedef float f32x4 __attribute__((ext_vector_type(4)));

#define MFMA16(a, b, c) __builtin_amdgcn_mfma_f32_16x16x32_bf16((a), (b), (c), 0, 0, 0)

#define GLOAD16(g, l)                                                        \
  __builtin_amdgcn_global_load_lds(                                          \
      (const __attribute__((address_space(1))) void*)(g),                    \
      (__attribute__((address_space(3))) void*)(l), 16, 0, 0)

static __device__ __forceinline__ u16 f2bf(float f) {
  union { float f; uint32_t u; } v;
  v.f = f;
  uint32_t u = v.u;
  return (u16)((u + 0x7FFFu + ((u >> 16) & 1u)) >> 16);  // RNE
}
static __device__ __forceinline__ float u2f(uint32_t u) {
  union { uint32_t u; float f; } v;
  v.u = u;
  return v.f;
}

// ---- workspace layout (u16 elements) ----
#define FEATT_ELEMS (8u * 98u * 98u * 256u)   // [b][h+1][w+1][c] bf16, zero halo
#define W1T_OFF     FEATT_ELEMS               // [oc][tap][cin] bf16: 256*2304
#define W1T_ELEMS   (256u * 2304u)
#define W2B_OFF     (W1T_OFF + W1T_ELEMS)     // [576][256] bf16
#define W2B_ELEMS   (576u * 256u)
#define X_OFF       (W2B_OFF + W2B_ELEMS)     // [73728][256] bf16

// ---------------- merged prep: halo zero | featT transpose | weights ------------
__global__ __launch_bounds__(256) void prep_all(const float* __restrict__ feat,
                                                const float* __restrict__ w1,
                                                const float* __restrict__ w2,
                                                u16* __restrict__ featT,
                                                u16* __restrict__ w1t,
                                                u16* __restrict__ w2b) {
  const int blk = blockIdx.x;
  const int t = threadIdx.x;
  if (blk < 388) {
    int tid = blk * 256 + t;
    int b = tid / (388 * 32);
    int rem = tid % (388 * 32);
    int pos = rem >> 5, v = rem & 31;
    int h, w;
    if (pos < 98) { h = 0; w = pos; }
    else if (pos < 196) { h = 97; w = pos - 98; }
    else if (pos < 292) { h = pos - 196 + 1; w = 0; }
    else { h = pos - 292 + 1; w = 97; }
    uint4* dst = (uint4*)(featT + (size_t)((b * 98 + h) * 98 + w) * 256 + v * 8);
    *dst = make_uint4(0, 0, 0, 0);
  } else if (blk < 4996) {
    int idx = blk - 388;
    int pt = idx % 144, ct = (idx / 144) & 3, b = idx / 576;
    const int p0 = pt * 64, c0 = ct * 64;
    __shared__ float tile[64][65];
    const int pj = t & 63, ci0 = t >> 6;
#pragma unroll
    for (int r = 0; r < 16; ++r) {
      int ci = r * 4 + ci0;
      tile[ci][pj] = feat[(b * 256 + c0 + ci) * 9216 + p0 + pj];
    }
    __syncthreads();
    const int pl = t >> 2, cc0 = (t & 3) * 16;
    const int pix = p0 + pl;
    const int h = pix / 96, w = pix % 96;
    uint32_t u[8];
#pragma unroll
    for (int i = 0; i < 8; ++i) {
      u16 lo = f2bf(tile[cc0 + 2 * i][pl]);
      u16 hi = f2bf(tile[cc0 + 2 * i + 1][pl]);
      u[i] = (uint32_t)lo | ((uint32_t)hi << 16);
    }
    uint4* dst = (uint4*)(featT + (size_t)((b * 98 + h + 1) * 98 + (w + 1)) * 256 + c0 + cc0);
    dst[0] = make_uint4(u[0], u[1], u[2], u[3]);
    dst[1] = make_uint4(u[4], u[5], u[6], u[7]);
  } else {
    int i = (blk - 4996) * 256 + t;
    if (i < 589824) {
      int oc = i / 2304, r = i % 2304;
      int tap = r >> 8, cin = r & 255;
      w1t[i] = f2bf(w1[(oc * 256 + cin) * 9 + tap]);
    } else {
      int j = i - 589824;
      if (j < 147456) w2b[j] = f2bf(w2[j]);
    }
  }
}

// ---------------- GEMM1 (r19-proven: r2 structure + XCD swizzle) ----------------
__global__ __launch_bounds__(512, 4) void gemm1(const u16* __restrict__ featT,
                                                const u16* __restrict__ w1t,
                                                const float* __restrict__ b1,
                                                u16* __restrict__ xout) {
  __shared__ __align__(16) u16 sA[128 * 64];  // 16KB
  __shared__ __align__(16) u16 sB[256 * 64];  // 32KB
  __shared__ float sb1[256];

  const int t = threadIdx.x;
  const int wave = t >> 6, lane = t & 63;
  const int bid = blockIdx.x;
  const int mt = (bid & 7) * 72 + (bid >> 3);  // bijective XCD swizzle (576%8==0)
  const int b = mt / 72;
  const int ip0 = (mt % 72) * 128;

  if (t < 256) sb1[t] = b1[t];

  const u16* aBase[2];
  const u16* bBase[4];
#pragma unroll
  for (int r = 0; r < 2; ++r) {
    int row = r * 64 + wave * 8 + (lane >> 3);  // 0..127
    int chunk = (lane & 7) ^ (row & 7);
    int ip = ip0 + row;
    int h = ip / 96, w = ip % 96;
    aBase[r] = featT + (size_t)((b * 98 + h + 1) * 98 + (w + 1)) * 256 + chunk * 8;
  }
#pragma unroll
  for (int r = 0; r < 4; ++r) {
    int row = wave * 32 + r * 8 + (lane >> 3);  // 0..255
    int chunk = (lane & 7) ^ (row & 7);
    bBase[r] = w1t + (size_t)row * 2304 + chunk * 8;
  }

  const int wm = wave >> 2, wn = wave & 3;
  int aoffs[4][2], boffs[4][2];
#pragma unroll
  for (int m = 0; m < 4; ++m) {
#pragma unroll
    for (int ki = 0; ki < 2; ++ki) {
      int kc = ki * 4 + (lane >> 4);
      int rowa = wm * 64 + m * 16 + (lane & 15);
      aoffs[m][ki] = rowa * 64 + ((kc ^ (rowa & 7)) * 8);
      int rowb = wn * 64 + m * 16 + (lane & 15);
      boffs[m][ki] = rowb * 64 + ((kc ^ (rowb & 7)) * 8);
    }
  }

  f32x4 acc[4][4];
#pragma unroll
  for (int m = 0; m < 4; ++m)
#pragma unroll
    for (int n = 0; n < 4; ++n) acc[m][n] = f32x4{0.f, 0.f, 0.f, 0.f};

  for (int kt = 0; kt < 36; ++kt) {
    int tap = kt >> 2;
    int dh = tap / 3 - 1, dw = tap % 3 - 1;
    int aoff = (dh * 98 + dw) * 256 + (kt & 3) * 64;
    int boff = kt * 64;
#pragma unroll
    for (int r = 0; r < 2; ++r) GLOAD16(aBase[r] + aoff, &sA[(r * 64 + wave * 8) * 64]);
#pragma unroll
    for (int r = 0; r < 4; ++r) GLOAD16(bBase[r] + boff, &sB[(wave * 32 + r * 8) * 64]);
    __syncthreads();
#pragma unroll
    for (int ki = 0; ki < 2; ++ki) {
      bf16x8 av[4], bv[4];
#pragma unroll
      for (int m = 0; m < 4; ++m) av[m] = *(const bf16x8*)&sA[aoffs[m][ki]];
#pragma unroll
      for (int n = 0; n < 4; ++n) bv[n] = *(const bf16x8*)&sB[boffs[n][ki]];
#pragma unroll
      for (int m = 0; m < 4; ++m)
#pragma unroll
        for (int n = 0; n < 4; ++n) acc[m][n] = MFMA16(av[m], bv[n], acc[m][n]);
    }
    __syncthreads();
  }

  const int pix0g = mt * 128;
#pragma unroll
  for (int m = 0; m < 4; ++m) {
    int pixl = wm * 64 + m * 16 + ((lane >> 4) << 2);
#pragma unroll
    for (int n = 0; n < 4; ++n) {
      int oc = wn * 64 + n * 16 + (lane & 15);
      float bias = sb1[oc];
      f32x4 v = acc[m][n];
#pragma unroll
      for (int j = 0; j < 4; ++j) {
        float val = v[j] + bias;
        val = val > 0.f ? val : 0.f;
        xout[(size_t)(pix0g + pixl + j) * 256 + oc] = f2bf(val);
      }
    }
  }
}

// ------- GEMM2FQ4: 4-buffer sW, barrier at EVEN units only (halved drains) ------
// Buffer cycle proof: top-of-even-u barrier drains stage(u),stage(u+1) (issued at
// u-2) and all reads through unit u-1. stage(u+2)/(u+3) issued in u write buffers
// last read in units u-2/u-1 -- both complete before the top-of-u barrier.
__global__ __launch_bounds__(512) void gemm2fq(const u16* __restrict__ xws,
                                               const u16* __restrict__ w2b,
                                               const float* __restrict__ b2g,
                                               const float* __restrict__ flow,
                                               float* __restrict__ out) {
  __shared__ __align__(16) u16 sW[4][9216];  // 4 x [144][64] bf16 = 73728 B
  __shared__ uint32_t sFlowP[1152];          // [9][128] packed (fy<<16)|fx, 4608 B
  __shared__ float sb2f[576];                // 2304 B  -> total 80640 B (2 blk/CU)

  const int t = threadIdx.x;
  const int wave = t >> 6, lane = t & 63;
  const int bid = blockIdx.x;
  const int mt = (bid & 7) * 72 + (bid >> 3);  // bijective XCD swizzle (576%8==0)
  const int b = mt / 72;
  const int ipl0 = (mt % 72) * 128;
  const int l15 = lane & 15, kc = lane >> 4;

  auto stageQ = [&](int u, int bufi) {
    int cI = u >> 2, kq = u & 3;
    if (t < 384) {  // wave-uniform (waves 0-5)
#pragma unroll
      for (int pass = 0; pass < 3; ++pass) {
        int c = pass * 384 + t;  // 0..1151
        int n = c >> 3, cl = c & 7;
        int cg = cl ^ (n & 7);
        int chan = (n >> 4) * 64 + cI * 16 + (n & 15);
        GLOAD16(w2b + (size_t)chan * 256 + kq * 64 + cg * 8,
                &sW[bufi][(pass * 384 + wave * 64) * 8]);
      }
    }
  };
  stageQ(0, 0);  // prologue: units 0 and 1 in flight over setup
  stageQ(1, 1);

  for (int i = t; i < 1152; i += 512) {
    int nf = i >> 7, p = i & 127;
    int ip = ipl0 + p;
    int h = ip / 96, w = ip % 96;
    int hh = h + nf / 3 - 1, ww = w + nf % 3 - 1;
    float vx = 0.f, vy = 0.f;
    if (hh >= 0 && hh < 96 && ww >= 0 && ww < 96) {
      vx = flow[b * 18432 + hh * 96 + ww];
      vy = flow[b * 18432 + 9216 + hh * 96 + ww];
    }
    sFlowP[i] = (uint32_t)f2bf(vx) | ((uint32_t)f2bf(vy) << 16);
  }
  for (int i = t; i < 576; i += 512) sb2f[i] = b2g[i];

  const int px = wave * 16 + l15;  // 0..127
  const u16* xr = &xws[((size_t)mt * 128 + px) * 256];
  bf16x8 areg[8];
#pragma unroll
  for (int s = 0; s < 8; ++s) areg[s] = *(const bf16x8*)&xr[(s * 4 + kc) * 8];

  const int iph = (ipl0 + px) / 96, ipw = (ipl0 + px) % 96;
  const size_t ob = ((size_t)(b * 2) * 768 + iph * 8) * 768 + ipw * 8;
  const int q0 = (kc & 1) * 4, pk = kc >> 1;

  uint32_t fp[9];
  f32x4 acc[9];
#pragma unroll
  for (int u = 0; u < 16; ++u) {
    if ((u & 1) == 0) {
      __syncthreads();  // drains stage(u),stage(u+1) + all reads through u-1
      if (u == 0) {
#pragma unroll
        for (int nf = 0; nf < 9; ++nf) fp[nf] = sFlowP[nf * 128 + px];
      }
      if (u < 14) {
        stageQ(u + 2, (u + 2) & 3);
        stageQ(u + 3, (u + 3) & 3);
      }
    }
    const int cI = u >> 2, kq = u & 3;
    if (kq == 0) {
#pragma unroll
      for (int nf = 0; nf < 9; ++nf) acc[nf] = f32x4{0.f, 0.f, 0.f, 0.f};
    }
    const u16* base = sW[u & 3];
    __builtin_amdgcn_s_setprio(1);
#pragma unroll
    for (int ki = 0; ki < 2; ++ki) {
      bf16x8 a = areg[kq * 2 + ki];  // static (loop fully unrolled)
      int kcc = ki * 4 + kc;         // 0..7 within the quarter
#pragma unroll
      for (int nf = 0; nf < 9; ++nf) {
        int n = nf * 16 + l15;
        bf16x8 wv = *(const bf16x8*)&base[n * 64 + ((kcc ^ (n & 7)) * 8)];
        acc[nf] = MFMA16(wv, a, acc[nf]);
      }
    }
    __builtin_amdgcn_s_setprio(0);
    if (kq == 3) {
      // slim softmax (logits bounded ~|3|) + combine; dense f32x4 stores
      f32x4 vx4, vy4;
#pragma unroll
      for (int j = 0; j < 4; ++j) {
        int pql = kc * 4 + j;
        float ssum = 0.f, fx = 0.f, fy = 0.f;
#pragma unroll
        for (int nf = 0; nf < 9; ++nf) {
          float e = __expf(acc[nf][j] + sb2f[nf * 64 + cI * 16 + pql]);
          ssum += e;
          fx += e * u2f(fp[nf] << 16);
          fy += e * u2f(fp[nf] & 0xFFFF0000u);
        }
        float sc = 8.0f / ssum;
        vx4[j] = fx * sc;
        vy4[j] = fy * sc;
      }
      int p = cI * 2 + pk;
      *(f32x4*)&out[ob + (size_t)p * 768 + q0] = vx4;
      *(f32x4*)&out[ob + 589824 + (size_t)p * 768 + q0] = vy4;
    }
  }
}

extern "C" void kernel_launch(void* const* d_in, const int* in_sizes, int n_in,
                              void* d_out, int out_size, void* d_ws, size_t ws_size,
                              hipStream_t stream) {
  const float* flow = (const float*)d_in[0];
  const float* feat = (const float*)d_in[1];
  const float* w1 = (const float*)d_in[2];
  const float* b1 = (const float*)d_in[3];
  const float* w2 = (const float*)d_in[4];
  const float* b2 = (const float*)d_in[5];
  float* out = (float*)d_out;
  u16* ws = (u16*)d_ws;
  u16* featT = ws;
  u16* w1t = ws + W1T_OFF;
  u16* w2b = ws + W2B_OFF;
  u16* xws = ws + X_OFF;

  prep_all<<<7876, 256, 0, stream>>>(feat, w1, w2, featT, w1t, w2b);
  gemm1<<<576, 512, 0, stream>>>(featT, w1t, b1, xws);
  gemm2fq<<<576, 512, 0, stream>>>(xws, w2b, b2, flow, out);
}